// Round 9
// baseline (318.176 us; speedup 1.0000x reference)
//
#include <hip/hip_runtime.h>

// GCN 2-layer: out = Ahat( relu( Ahat(x) W1 + b1 ) W2 ) + b2, Ahat = D^-1/2 (A+I) D^-1/2.
// Ahat(x W1) = (Ahat x) W1 -> aggregate in 64-dim space both times.
// N=100000, E=1.6M, dims 64->128->64.
//
// R8 post-mortem: k_agg_csr x2 dominate (62us each); every gather misses per-XCD
// L2 (FETCH 199MB), plus 1.6M random 4B dinv[s] gathers ride along. R9:
// (1) prescale h~ = dinv*h once per layer -> agg is pure gather+add;
// (2) unroll x8 (2x outstanding gathers); (3) pairs packed to 4B
// (src<<9 | local_dst), halving bucket/finish traffic.

#define DIM 64
#define NB 256          // dst-range buckets
#define SPAN 391        // ceil(100000/256); NB*SPAN >= N; SPAN < 512
#define BK_TILE 4096
#define BK_PER 16       // edges per thread in k_bucket

__device__ __forceinline__ void atomAddF(float* p, float v) {
    unsafeAtomicAdd(p, v);
}

// ---------------- bucket totals ----------------
__global__ __launch_bounds__(256) void k_zero256(int* p) {
    p[threadIdx.x] = 0;
}
// LDS-privatized 256-bin histogram of dst/SPAN
__global__ __launch_bounds__(256) void k_hist256(const int* __restrict__ ei,
                                                 int* __restrict__ bucketCnt, int E) {
    __shared__ int h[NB];
    const int tid = threadIdx.x;
    h[tid] = 0;
    __syncthreads();
    const int base = blockIdx.x * BK_TILE;
    #pragma unroll
    for (int j = 0; j < BK_TILE; j += 256) {
        int e = base + j + tid;
        if (e < E) atomicAdd(&h[(unsigned)ei[E + e] / (unsigned)SPAN], 1);
    }
    __syncthreads();
    if (h[tid]) atomicAdd(&bucketCnt[tid], h[tid]);
}
// one block: exclusive scan of 256 totals -> bucketBase[0..256]; seed gcur
__global__ __launch_bounds__(256) void k_scan_b(const int* __restrict__ bucketCnt,
                                                int* __restrict__ bucketBase,
                                                int* __restrict__ gcur) {
    __shared__ int s[NB];
    const int tid = threadIdx.x;
    int v = bucketCnt[tid];
    s[tid] = v;
    __syncthreads();
    for (int off = 1; off < NB; off <<= 1) {
        int t = (tid >= off) ? s[tid - off] : 0;
        __syncthreads();
        s[tid] += t;
        __syncthreads();
    }
    int ex = s[tid] - v;
    bucketBase[tid] = ex;
    gcur[tid] = ex;
    if (tid == NB - 1) bucketBase[NB] = s[NB - 1];
}

// Phase A: tile multisplit -> bucket-grouped packed edges, coalesced writes.
// packed = (src << 9) | (dst - bucket*SPAN);  src < 2^17, local dst < 512.
__global__ __launch_bounds__(256) void k_bucket(const int* __restrict__ ei,
                                                int* __restrict__ gcur,
                                                unsigned* __restrict__ pairs, int E) {
    __shared__ int scn[NB];
    __shared__ int run[NB];
    __shared__ int lbase[NB];
    __shared__ int gbase[NB];
    __shared__ unsigned stage[BK_TILE];    // 16 KB
    __shared__ unsigned char bkt[BK_TILE]; // 4 KB
    const int tid = threadIdx.x;
    const int base = blockIdx.x * BK_TILE;

    scn[tid] = 0;
    __syncthreads();

    unsigned pv[BK_PER];
    int bv[BK_PER];
    #pragma unroll
    for (int j = 0; j < BK_PER; ++j) {
        int e = base + j * 256 + tid;
        if (e < E) {
            unsigned s = (unsigned)ei[e];
            unsigned d = (unsigned)ei[E + e];
            int b = (int)(d / (unsigned)SPAN);
            bv[j] = b;
            pv[j] = (s << 9) | (d - (unsigned)b * SPAN);
            atomicAdd(&scn[b], 1);
        } else bv[j] = -1;
    }
    __syncthreads();
    int c = scn[tid];
    for (int off = 1; off < 256; off <<= 1) {
        int t = (tid >= off) ? scn[tid - off] : 0;
        __syncthreads();
        scn[tid] += t;
        __syncthreads();
    }
    int ex = scn[tid] - c;
    lbase[tid] = ex;
    run[tid] = ex;
    if (c > 0) gbase[tid] = atomicAdd(&gcur[tid], c);
    __syncthreads();

    #pragma unroll
    for (int j = 0; j < BK_PER; ++j) {
        if (bv[j] >= 0) {
            int p = atomicAdd(&run[bv[j]], 1);
            stage[p] = pv[j];
            bkt[p] = (unsigned char)bv[j];
        }
    }
    __syncthreads();

    int total = min(BK_TILE, E - base);
    for (int i = tid; i < total; i += 256) {
        int bb = bkt[i];
        pairs[gbase[bb] + (i - lbase[bb])] = stage[i];
    }
}

// Phase B: one block per bucket. Local node hist -> scan -> row_ptr/dinv/col.
__global__ __launch_bounds__(256) void k_finish(const unsigned* __restrict__ pairs,
                                                const int* __restrict__ bucketBase,
                                                int* __restrict__ row_ptr,
                                                float* __restrict__ dinv,
                                                int* __restrict__ col, int N) {
    __shared__ int lh[512];
    __shared__ int sa[512];
    __shared__ int sb[512];
    __shared__ int lcur[SPAN];
    const int tid = threadIdx.x;
    const int b = blockIdx.x;
    const int lo = b * SPAN;
    const int hi = min(lo + SPAN, N);
    const int nn = hi - lo;
    const int p0 = bucketBase[b];
    const int p1 = bucketBase[b + 1];

    for (int i = tid; i < 512; i += 256) lh[i] = 0;
    __syncthreads();
    for (int e = p0 + tid; e < p1; e += 256)
        atomicAdd(&lh[pairs[e] & 511u], 1);
    __syncthreads();
    int* cur = sa;
    int* nxt = sb;
    for (int i = tid; i < 512; i += 256) sa[i] = lh[i];
    __syncthreads();
    for (int off = 1; off < 512; off <<= 1) {
        for (int i = tid; i < 512; i += 256)
            nxt[i] = cur[i] + ((i >= off) ? cur[i - off] : 0);
        __syncthreads();
        int* t = cur; cur = nxt; nxt = t;
    }
    for (int i = tid; i < nn; i += 256) {
        int cnt  = lh[i];
        int base = p0 + cur[i] - cnt;
        row_ptr[lo + i] = base;
        lcur[i] = base;
        dinv[lo + i] = rsqrtf(1.0f + (float)cnt);   // +1 self-loop
    }
    if (b == NB - 1 && tid == 0) row_ptr[N] = p1;
    __syncthreads();
    for (int e = p0 + tid; e < p1; e += 256) {
        unsigned pr = pairs[e];
        int pos = atomicAdd(&lcur[pr & 511u], 1);
        col[pos] = (int)(pr >> 9);
    }
}

// ---------------- prescale: ph = dinv ⊙ x ----------------
__global__ __launch_bounds__(256) void k_prescale(const float* __restrict__ x,
                                                  const float* __restrict__ dinv,
                                                  float* __restrict__ ph, int n) {
    int g = blockIdx.x * 256 + threadIdx.x;
    int i = g >> 4, c = g & 15;
    if (i >= n) return;
    float di = dinv[i];
    float4 v = ((const float4*)x)[(long)i * 16 + c];
    ((float4*)ph)[(long)i * 16 + c] =
        make_float4(v.x * di, v.y * di, v.z * di, v.w * di);
}

// ---------------- CSR aggregation: pure gather+add, unroll x8 ----------------
// out[d] = dinv[d] * ( ph[d] + sum_{s in N(d)} ph[s] ) [+ b]   (ph prescaled)
template<bool BIAS>
__global__ __launch_bounds__(256) void k_agg_csr(const int* __restrict__ row_ptr,
                                                 const int* __restrict__ col,
                                                 const float* __restrict__ dinv,
                                                 const float* __restrict__ ph,
                                                 const float* __restrict__ b,
                                                 float* __restrict__ out, int n) {
    int g = blockIdx.x * 16 + (threadIdx.x >> 4);
    if (g >= n) return;
    int lane = threadIdx.x & 15;
    const float4* h4 = (const float4*)ph;
    float4 a0 = h4[(long)g * 16 + lane];   // self term (prescaled)
    float4 a1 = make_float4(0.f, 0.f, 0.f, 0.f);
    float4 a2 = a1, a3 = a1, a4 = a1, a5 = a1, a6 = a1, a7 = a1;
    int e = row_ptr[g], e1 = row_ptr[g + 1];
    for (; e + 8 <= e1; e += 8) {
        int s0 = col[e], s1 = col[e + 1], s2 = col[e + 2], s3 = col[e + 3];
        int s4 = col[e + 4], s5 = col[e + 5], s6 = col[e + 6], s7 = col[e + 7];
        float4 v0 = h4[(long)s0 * 16 + lane];
        float4 v1 = h4[(long)s1 * 16 + lane];
        float4 v2 = h4[(long)s2 * 16 + lane];
        float4 v3 = h4[(long)s3 * 16 + lane];
        float4 v4 = h4[(long)s4 * 16 + lane];
        float4 v5 = h4[(long)s5 * 16 + lane];
        float4 v6 = h4[(long)s6 * 16 + lane];
        float4 v7 = h4[(long)s7 * 16 + lane];
        a0.x += v0.x; a0.y += v0.y; a0.z += v0.z; a0.w += v0.w;
        a1.x += v1.x; a1.y += v1.y; a1.z += v1.z; a1.w += v1.w;
        a2.x += v2.x; a2.y += v2.y; a2.z += v2.z; a2.w += v2.w;
        a3.x += v3.x; a3.y += v3.y; a3.z += v3.z; a3.w += v3.w;
        a4.x += v4.x; a4.y += v4.y; a4.z += v4.z; a4.w += v4.w;
        a5.x += v5.x; a5.y += v5.y; a5.z += v5.z; a5.w += v5.w;
        a6.x += v6.x; a6.y += v6.y; a6.z += v6.z; a6.w += v6.w;
        a7.x += v7.x; a7.y += v7.y; a7.z += v7.z; a7.w += v7.w;
    }
    for (; e + 2 <= e1; e += 2) {
        int s0 = col[e], s1 = col[e + 1];
        float4 v0 = h4[(long)s0 * 16 + lane];
        float4 v1 = h4[(long)s1 * 16 + lane];
        a0.x += v0.x; a0.y += v0.y; a0.z += v0.z; a0.w += v0.w;
        a1.x += v1.x; a1.y += v1.y; a1.z += v1.z; a1.w += v1.w;
    }
    if (e < e1) {
        float4 v0 = h4[(long)col[e] * 16 + lane];
        a0.x += v0.x; a0.y += v0.y; a0.z += v0.z; a0.w += v0.w;
    }
    float di = dinv[g];
    float4 r;
    r.x = ((a0.x + a1.x) + (a2.x + a3.x)) + ((a4.x + a5.x) + (a6.x + a7.x));
    r.y = ((a0.y + a1.y) + (a2.y + a3.y)) + ((a4.y + a5.y) + (a6.y + a7.y));
    r.z = ((a0.z + a1.z) + (a2.z + a3.z)) + ((a4.z + a5.z) + (a6.z + a7.z));
    r.w = ((a0.w + a1.w) + (a2.w + a3.w)) + ((a4.w + a5.w) + (a6.w + a7.w));
    r.x *= di; r.y *= di; r.z *= di; r.w *= di;
    if (BIAS) {
        float4 bv = ((const float4*)b)[lane];
        r.x += bv.x; r.y += bv.y; r.z += bv.z; r.w += bv.w;
    }
    ((float4*)out)[(long)g * 16 + lane] = r;
}

// ---------------- fused MLP: T = [dscale ⊙] relu(G @ W1 + b1) @ W2 ----------------
// 64-row tile, 256 threads, 4 rows x 8 cols per thread. In-place capable (T==G).
template<bool SCALE>
__global__ __launch_bounds__(256) void k_fused_mlp(const float* __restrict__ G,   // [N,64]
                                                   const float* __restrict__ W1,  // [64,128]
                                                   const float* __restrict__ b1,  // [128]
                                                   const float* __restrict__ W2,  // [128,64]
                                                   const float* __restrict__ dscale,
                                                   float* __restrict__ T,         // [N,64]
                                                   int M) {
    __shared__ float Ws[64 * 128];   // 32 KB
    __shared__ float HA[64 * 132];   // 33 KB: A tile (stride 68), then H tile (stride 132)
    const int tid = threadIdx.x;
    const int row0 = blockIdx.x * 64;
    const int ty = tid >> 4;
    const int tx = tid & 15;

    #pragma unroll
    for (int l = 0; l < 4; ++l) {
        int idx = l * 256 + tid;
        int r = idx >> 4, cv = idx & 15;
        int gr = row0 + r;
        float4 v = make_float4(0.f, 0.f, 0.f, 0.f);
        if (gr < M) v = *(const float4*)&G[(long)gr * DIM + cv * 4];
        *(float4*)&HA[r * 68 + cv * 4] = v;
    }
    #pragma unroll
    for (int l = 0; l < 8; ++l) {
        int idx = (l * 256 + tid) * 4;
        *(float4*)&Ws[idx] = *(const float4*)&W1[idx];
    }
    __syncthreads();

    float4 accA[4], accB[4];
    #pragma unroll
    for (int i = 0; i < 4; ++i) {
        accA[i] = make_float4(0.f, 0.f, 0.f, 0.f);
        accB[i] = make_float4(0.f, 0.f, 0.f, 0.f);
    }
    for (int k4 = 0; k4 < 64; k4 += 4) {
        float4 a[4];
        #pragma unroll
        for (int i = 0; i < 4; ++i) a[i] = *(const float4*)&HA[(ty * 4 + i) * 68 + k4];
        #pragma unroll
        for (int kk = 0; kk < 4; ++kk) {
            const float* wr = &Ws[(k4 + kk) * 128 + tx * 8];
            float4 wA = *(const float4*)wr;
            float4 wB = *(const float4*)(wr + 4);
            #pragma unroll
            for (int i = 0; i < 4; ++i) {
                float ak = (&a[i].x)[kk];
                accA[i].x += ak * wA.x; accA[i].y += ak * wA.y;
                accA[i].z += ak * wA.z; accA[i].w += ak * wA.w;
                accB[i].x += ak * wB.x; accB[i].y += ak * wB.y;
                accB[i].z += ak * wB.z; accB[i].w += ak * wB.w;
            }
        }
    }
    __syncthreads();

    {
        float4 bA = *(const float4*)&b1[tx * 8];
        float4 bB = *(const float4*)&b1[tx * 8 + 4];
        #pragma unroll
        for (int i = 0; i < 4; ++i) {
            float4 hA = make_float4(fmaxf(accA[i].x + bA.x, 0.f), fmaxf(accA[i].y + bA.y, 0.f),
                                    fmaxf(accA[i].z + bA.z, 0.f), fmaxf(accA[i].w + bA.w, 0.f));
            float4 hB = make_float4(fmaxf(accB[i].x + bB.x, 0.f), fmaxf(accB[i].y + bB.y, 0.f),
                                    fmaxf(accB[i].z + bB.z, 0.f), fmaxf(accB[i].w + bB.w, 0.f));
            *(float4*)&HA[(ty * 4 + i) * 132 + tx * 8 + 0] = hA;
            *(float4*)&HA[(ty * 4 + i) * 132 + tx * 8 + 4] = hB;
        }
    }
    #pragma unroll
    for (int l = 0; l < 8; ++l) {
        int idx = (l * 256 + tid) * 4;
        *(float4*)&Ws[idx] = *(const float4*)&W2[idx];
    }
    __syncthreads();

    float4 o[4];
    #pragma unroll
    for (int i = 0; i < 4; ++i) o[i] = make_float4(0.f, 0.f, 0.f, 0.f);
    for (int k4 = 0; k4 < 128; k4 += 4) {
        float4 a[4];
        #pragma unroll
        for (int i = 0; i < 4; ++i) a[i] = *(const float4*)&HA[(ty * 4 + i) * 132 + k4];
        #pragma unroll
        for (int kk = 0; kk < 4; ++kk) {
            float4 w = *(const float4*)&Ws[(k4 + kk) * 64 + tx * 4];
            #pragma unroll
            for (int i = 0; i < 4; ++i) {
                float ak = (&a[i].x)[kk];
                o[i].x += ak * w.x; o[i].y += ak * w.y;
                o[i].z += ak * w.z; o[i].w += ak * w.w;
            }
        }
    }
    #pragma unroll
    for (int i = 0; i < 4; ++i) {
        int gr = row0 + ty * 4 + i;
        if (gr < M) {
            float4 v = o[i];
            if (SCALE) {
                float sc = dscale[gr];
                v.x *= sc; v.y *= sc; v.z *= sc; v.w *= sc;
            }
            *(float4*)&T[(long)gr * DIM + tx * 4] = v;
        }
    }
}

// ---------------- fallback path (atomic scatter; used only if ws too small) ----------------
__global__ __launch_bounds__(256) void k_init_deg(float* deg, int n) {
    int i = blockIdx.x * 256 + threadIdx.x;
    if (i < n) deg[i] = 1.0f;
}
__global__ __launch_bounds__(256) void k_count_deg(const int* __restrict__ ei, float* deg, int E) {
    int e = blockIdx.x * 256 + threadIdx.x;
    if (e < E) atomAddF(&deg[ei[E + e]], 1.0f);
}
__global__ __launch_bounds__(256) void k_rsqrt(float* deg, int n) {
    int i = blockIdx.x * 256 + threadIdx.x;
    if (i < n) deg[i] = rsqrtf(deg[i]);
}
template<bool BIAS>
__global__ __launch_bounds__(256) void k_self(const float* __restrict__ src,
                                              const float* __restrict__ dinv,
                                              const float* __restrict__ b,
                                              float* __restrict__ out, int n) {
    int g = blockIdx.x * 256 + threadIdx.x;
    int i = g >> 4, c = g & 15;
    if (i >= n) return;
    float di = dinv[i];
    float s = di * di;
    float4 v = *(const float4*)&src[(long)i * DIM + c * 4];
    float4 r = make_float4(v.x * s, v.y * s, v.z * s, v.w * s);
    if (BIAS) {
        float4 bv = *(const float4*)&b[c * 4];
        r.x += bv.x; r.y += bv.y; r.z += bv.z; r.w += bv.w;
    }
    *(float4*)&out[(long)i * DIM + c * 4] = r;
}
__global__ __launch_bounds__(256) void k_edge_agg(const int* __restrict__ ei,
                                                  const float* __restrict__ dinv,
                                                  const float* __restrict__ h,
                                                  float* __restrict__ out, int E) {
    int t = threadIdx.x;
    int e = blockIdx.x * 16 + (t >> 4);
    if (e >= E) return;
    int lane = t & 15;
    int s = ei[e];
    int d = ei[E + e];
    float norm = dinv[s] * dinv[d];
    float4 hv = *(const float4*)&h[(long)s * DIM + lane * 4];
    float* o = &out[(long)d * DIM + lane * 4];
    atomAddF(o + 0, hv.x * norm);
    atomAddF(o + 1, hv.y * norm);
    atomAddF(o + 2, hv.z * norm);
    atomAddF(o + 3, hv.w * norm);
}

extern "C" void kernel_launch(void* const* d_in, const int* in_sizes, int n_in,
                              void* d_out, int out_size, void* d_ws, size_t ws_size,
                              hipStream_t stream) {
    const float* x  = (const float*)d_in[0];
    const int*   ei = (const int*)d_in[1];   // [2,E] int32
    const float* W1 = (const float*)d_in[2];
    const float* b1 = (const float*)d_in[3];
    const float* W2 = (const float*)d_in[4];
    const float* b2 = (const float*)d_in[5];
    float* out = (float*)d_out;

    const int N = in_sizes[0] / DIM;   // 100000
    const int E = in_sizes[1] / 2;     // 1600000

    const int gn   = (N + 255) / 256;
    const int ge   = (E + 255) / 256;
    const int gagg = (N + 15) / 16;
    const int gmlp = (N + 63) / 64;
    const int grow = ((long)N * 16 + 255) / 256;   // 16 lanes/row kernels
    const int gbk  = (E + BK_TILE - 1) / BK_TILE;

    // ws layout (256B-aligned bump). pairs aliases buf (pairs dead before agg1 writes buf).
    size_t off = 0;
    auto bump = [&](size_t bytes) { size_t o = off; off = (off + bytes + 255) & ~(size_t)255; return o; };
    size_t o_dinv   = bump((size_t)N * 4);
    size_t o_rowptr = bump((size_t)(N + 1) * 4);
    size_t o_bcnt   = bump(NB * 4);
    size_t o_bbase  = bump((NB + 1) * 4);
    size_t o_gcur   = bump(NB * 4);
    size_t o_col    = bump((size_t)E * 4);
    size_t o_buf    = bump((size_t)N * DIM * 4);   // >= E*4 (25.6MB >= 6.4MB)
    size_t need_csr = off;

    char* ws = (char*)d_ws;

    if (ws_size >= need_csr) {
        float*    dinv   = (float*)(ws + o_dinv);
        int*      rowptr = (int*)(ws + o_rowptr);
        int*      bcnt   = (int*)(ws + o_bcnt);
        int*      bbase  = (int*)(ws + o_bbase);
        int*      gcur   = (int*)(ws + o_gcur);
        int*      col    = (int*)(ws + o_col);
        float*    buf    = (float*)(ws + o_buf);
        unsigned* pairs  = (unsigned*)(ws + o_buf);   // alias (dead before agg1)

        k_zero256<<<1, 256, 0, stream>>>(bcnt);
        k_hist256<<<gbk, 256, 0, stream>>>(ei, bcnt, E);
        k_scan_b<<<1, 256, 0, stream>>>(bcnt, bbase, gcur);
        k_bucket<<<gbk, 256, 0, stream>>>(ei, gcur, pairs, E);
        k_finish<<<NB, 256, 0, stream>>>(pairs, bbase, rowptr, dinv, col, N);

        // d_out = dinv ⊙ x
        k_prescale<<<grow, 256, 0, stream>>>(x, dinv, out, N);
        // buf = Ahat x  = dinv[d]*(x~[d] + sum x~[s])
        k_agg_csr<false><<<gagg, 256, 0, stream>>>(rowptr, col, dinv, out, nullptr, buf, N);
        // buf = dinv ⊙ ( relu(buf W1 + b1) W2 )   (in-place, tile-local)
        k_fused_mlp<true><<<gmlp, 256, 0, stream>>>(buf, W1, b1, W2, dinv, buf, N);
        // d_out = dinv[d]*(buf[d] + sum buf[s]) + b2
        k_agg_csr<true><<<gagg, 256, 0, stream>>>(rowptr, col, dinv, buf, b2, out, N);
    } else {
        // -------- fallback (atomic scatter) --------
        float* dinv = (float*)ws;
        float* buf  = (float*)(ws + 512 * 1024);
        int gedge = (E + 15) / 16;

        k_init_deg<<<gn, 256, 0, stream>>>(dinv, N);
        k_count_deg<<<ge, 256, 0, stream>>>(ei, dinv, E);
        k_rsqrt<<<gn, 256, 0, stream>>>(dinv, N);

        k_self<false><<<grow, 256, 0, stream>>>(x, dinv, nullptr, buf, N);
        k_edge_agg<<<gedge, 256, 0, stream>>>(ei, dinv, x, buf, E);
        k_fused_mlp<false><<<gmlp, 256, 0, stream>>>(buf, W1, b1, W2, nullptr, buf, N);
        k_self<true><<<grow, 256, 0, stream>>>(buf, dinv, b2, out, N);
        k_edge_agg<<<gedge, 256, 0, stream>>>(ei, dinv, buf, out, E);
    }
}

// Round 10
// 254.825 us; speedup vs baseline: 1.2486x; 1.2486x over previous
//
#include <hip/hip_runtime.h>
#include <hip/hip_fp16.h>

// GCN 2-layer: out = Ahat( relu( Ahat(x) W1 + b1 ) W2 ) + b2, Ahat = D^-1/2 (A+I) D^-1/2.
// Ahat(x W1) = (Ahat x) W1 -> aggregate in 64-dim space both times.
// N=100000, E=1.6M, dims 64->128->64.
//
// R9 post-mortem: prescale/unroll did NOT move k_agg_csr (62.6us, FETCH 191MB):
// it is bytes-bound at the random-gather L2-reuse limit (~2x of the 410MB fp32
// floor). R10: halve the bytes -- gather payload in fp16 (128B rows), fp32
// accumulate. 8 lanes/edge x float4(=8 halves): 8 edges in flight per wave instr.
// Precision: fp16 rel err 5e-4 adds ~1-2e-3 abs; margin is 1.95e-3 vs 1.06e-2.

#define DIM 64
#define NB 256          // dst-range buckets
#define SPAN 391        // ceil(100000/256); NB*SPAN >= N; SPAN < 512
#define BK_TILE 4096
#define BK_PER 16       // edges per thread in k_bucket

__device__ __forceinline__ void atomAddF(float* p, float v) {
    unsafeAtomicAdd(p, v);
}

// 8 halves (packed in float4) -> add into 8 fp32 accumulators
__device__ __forceinline__ void h8_add(const float4 v, float* acc) {
    const __half2* hp = (const __half2*)&v;
    #pragma unroll
    for (int i = 0; i < 4; ++i) {
        float2 t = __half22float2(hp[i]);
        acc[2 * i] += t.x;
        acc[2 * i + 1] += t.y;
    }
}
// 8 fp32 -> 8 halves packed in a float4
__device__ __forceinline__ float4 f8_to_h8(const float* f) {
    __half2 hh[4];
    hh[0] = __float22half2_rn(make_float2(f[0], f[1]));
    hh[1] = __float22half2_rn(make_float2(f[2], f[3]));
    hh[2] = __float22half2_rn(make_float2(f[4], f[5]));
    hh[3] = __float22half2_rn(make_float2(f[6], f[7]));
    return *(float4*)hh;
}

// ---------------- bucket totals ----------------
__global__ __launch_bounds__(256) void k_zero256(int* p) {
    p[threadIdx.x] = 0;
}
__global__ __launch_bounds__(256) void k_hist256(const int* __restrict__ ei,
                                                 int* __restrict__ bucketCnt, int E) {
    __shared__ int h[NB];
    const int tid = threadIdx.x;
    h[tid] = 0;
    __syncthreads();
    const int base = blockIdx.x * BK_TILE;
    #pragma unroll
    for (int j = 0; j < BK_TILE; j += 256) {
        int e = base + j + tid;
        if (e < E) atomicAdd(&h[(unsigned)ei[E + e] / (unsigned)SPAN], 1);
    }
    __syncthreads();
    if (h[tid]) atomicAdd(&bucketCnt[tid], h[tid]);
}
__global__ __launch_bounds__(256) void k_scan_b(const int* __restrict__ bucketCnt,
                                                int* __restrict__ bucketBase,
                                                int* __restrict__ gcur) {
    __shared__ int s[NB];
    const int tid = threadIdx.x;
    int v = bucketCnt[tid];
    s[tid] = v;
    __syncthreads();
    for (int off = 1; off < NB; off <<= 1) {
        int t = (tid >= off) ? s[tid - off] : 0;
        __syncthreads();
        s[tid] += t;
        __syncthreads();
    }
    int ex = s[tid] - v;
    bucketBase[tid] = ex;
    gcur[tid] = ex;
    if (tid == NB - 1) bucketBase[NB] = s[NB - 1];
}

// Phase A: tile multisplit -> bucket-grouped packed edges ((src<<9)|local_dst).
__global__ __launch_bounds__(256) void k_bucket(const int* __restrict__ ei,
                                                int* __restrict__ gcur,
                                                unsigned* __restrict__ pairs, int E) {
    __shared__ int scn[NB];
    __shared__ int run[NB];
    __shared__ int lbase[NB];
    __shared__ int gbase[NB];
    __shared__ unsigned stage[BK_TILE];
    __shared__ unsigned char bkt[BK_TILE];
    const int tid = threadIdx.x;
    const int base = blockIdx.x * BK_TILE;

    scn[tid] = 0;
    __syncthreads();

    unsigned pv[BK_PER];
    int bv[BK_PER];
    #pragma unroll
    for (int j = 0; j < BK_PER; ++j) {
        int e = base + j * 256 + tid;
        if (e < E) {
            unsigned s = (unsigned)ei[e];
            unsigned d = (unsigned)ei[E + e];
            int b = (int)(d / (unsigned)SPAN);
            bv[j] = b;
            pv[j] = (s << 9) | (d - (unsigned)b * SPAN);
            atomicAdd(&scn[b], 1);
        } else bv[j] = -1;
    }
    __syncthreads();
    int c = scn[tid];
    for (int off = 1; off < 256; off <<= 1) {
        int t = (tid >= off) ? scn[tid - off] : 0;
        __syncthreads();
        scn[tid] += t;
        __syncthreads();
    }
    int ex = scn[tid] - c;
    lbase[tid] = ex;
    run[tid] = ex;
    if (c > 0) gbase[tid] = atomicAdd(&gcur[tid], c);
    __syncthreads();

    #pragma unroll
    for (int j = 0; j < BK_PER; ++j) {
        if (bv[j] >= 0) {
            int p = atomicAdd(&run[bv[j]], 1);
            stage[p] = pv[j];
            bkt[p] = (unsigned char)bv[j];
        }
    }
    __syncthreads();

    int total = min(BK_TILE, E - base);
    for (int i = tid; i < total; i += 256) {
        int bb = bkt[i];
        pairs[gbase[bb] + (i - lbase[bb])] = stage[i];
    }
}

// Phase B: one block per bucket. Local node hist -> scan -> row_ptr/dinv/col.
__global__ __launch_bounds__(256) void k_finish(const unsigned* __restrict__ pairs,
                                                const int* __restrict__ bucketBase,
                                                int* __restrict__ row_ptr,
                                                float* __restrict__ dinv,
                                                int* __restrict__ col, int N) {
    __shared__ int lh[512];
    __shared__ int sa[512];
    __shared__ int sb[512];
    __shared__ int lcur[SPAN];
    const int tid = threadIdx.x;
    const int b = blockIdx.x;
    const int lo = b * SPAN;
    const int hi = min(lo + SPAN, N);
    const int nn = hi - lo;
    const int p0 = bucketBase[b];
    const int p1 = bucketBase[b + 1];

    for (int i = tid; i < 512; i += 256) lh[i] = 0;
    __syncthreads();
    for (int e = p0 + tid; e < p1; e += 256)
        atomicAdd(&lh[pairs[e] & 511u], 1);
    __syncthreads();
    int* cur = sa;
    int* nxt = sb;
    for (int i = tid; i < 512; i += 256) sa[i] = lh[i];
    __syncthreads();
    for (int off = 1; off < 512; off <<= 1) {
        for (int i = tid; i < 512; i += 256)
            nxt[i] = cur[i] + ((i >= off) ? cur[i - off] : 0);
        __syncthreads();
        int* t = cur; cur = nxt; nxt = t;
    }
    for (int i = tid; i < nn; i += 256) {
        int cnt  = lh[i];
        int base = p0 + cur[i] - cnt;
        row_ptr[lo + i] = base;
        lcur[i] = base;
        dinv[lo + i] = rsqrtf(1.0f + (float)cnt);   // +1 self-loop
    }
    if (b == NB - 1 && tid == 0) row_ptr[N] = p1;
    __syncthreads();
    for (int e = p0 + tid; e < p1; e += 256) {
        unsigned pr = pairs[e];
        int pos = atomicAdd(&lcur[pr & 511u], 1);
        col[pos] = (int)(pr >> 9);
    }
}

// ---------------- prescale: Y = half(dinv ⊙ x), 8 cols/thread ----------------
__global__ __launch_bounds__(256) void k_prescale_h(const float* __restrict__ x,
                                                    const float* __restrict__ dinv,
                                                    __half* __restrict__ Y, int n) {
    int g = blockIdx.x * 256 + threadIdx.x;
    int i = g >> 3, seg = g & 7;
    if (i >= n) return;
    float di = dinv[i];
    float4 a = ((const float4*)x)[(long)i * 16 + seg * 2];
    float4 b = ((const float4*)x)[(long)i * 16 + seg * 2 + 1];
    float f[8] = {a.x * di, a.y * di, a.z * di, a.w * di,
                  b.x * di, b.y * di, b.z * di, b.w * di};
    ((float4*)Y)[(long)i * 8 + seg] = f8_to_h8(f);
}

// ---------------- fp16 CSR aggregation: pure gather+add ----------------
// out[d] = dinv[d]*(ph[d] + sum ph[s]) [+bias].  8 lanes/row, 32 nodes/block.
// OUT_HALF: write half row (for MLP input); else float row + bias (final out).
template<bool BIAS, bool OUT_HALF>
__global__ __launch_bounds__(256) void k_agg_h(const int* __restrict__ row_ptr,
                                               const int* __restrict__ col,
                                               const float* __restrict__ dinv,
                                               const __half* __restrict__ ph,
                                               const float* __restrict__ bias,
                                               void* __restrict__ outv, int n) {
    int g = blockIdx.x * 32 + (threadIdx.x >> 3);
    if (g >= n) return;
    int lane = threadIdx.x & 7;
    const float4* h4 = (const float4*)ph;   // 8 x 16B (8 halves) per row
    float accA[8] = {}, accB[8] = {};
    h8_add(h4[(long)g * 8 + lane], accA);   // self term (prescaled)
    int e = row_ptr[g], e1 = row_ptr[g + 1];
    for (; e + 8 <= e1; e += 8) {
        int s0 = col[e], s1 = col[e + 1], s2 = col[e + 2], s3 = col[e + 3];
        int s4 = col[e + 4], s5 = col[e + 5], s6 = col[e + 6], s7 = col[e + 7];
        float4 v0 = h4[(long)s0 * 8 + lane];
        float4 v1 = h4[(long)s1 * 8 + lane];
        float4 v2 = h4[(long)s2 * 8 + lane];
        float4 v3 = h4[(long)s3 * 8 + lane];
        float4 v4 = h4[(long)s4 * 8 + lane];
        float4 v5 = h4[(long)s5 * 8 + lane];
        float4 v6 = h4[(long)s6 * 8 + lane];
        float4 v7 = h4[(long)s7 * 8 + lane];
        h8_add(v0, accA); h8_add(v1, accB);
        h8_add(v2, accA); h8_add(v3, accB);
        h8_add(v4, accA); h8_add(v5, accB);
        h8_add(v6, accA); h8_add(v7, accB);
    }
    for (; e + 2 <= e1; e += 2) {
        float4 v0 = h4[(long)col[e] * 8 + lane];
        float4 v1 = h4[(long)col[e + 1] * 8 + lane];
        h8_add(v0, accA); h8_add(v1, accB);
    }
    if (e < e1) h8_add(h4[(long)col[e] * 8 + lane], accA);

    float di = dinv[g];
    float r[8];
    #pragma unroll
    for (int i = 0; i < 8; ++i) r[i] = (accA[i] + accB[i]) * di;
    if (OUT_HALF) {
        ((float4*)outv)[(long)g * 8 + lane] = f8_to_h8(r);
    } else {
        if (BIAS) {
            float4 b0 = ((const float4*)bias)[lane * 2];
            float4 b1 = ((const float4*)bias)[lane * 2 + 1];
            r[0] += b0.x; r[1] += b0.y; r[2] += b0.z; r[3] += b0.w;
            r[4] += b1.x; r[5] += b1.y; r[6] += b1.z; r[7] += b1.w;
        }
        ((float4*)outv)[(long)g * 16 + lane * 2]     = make_float4(r[0], r[1], r[2], r[3]);
        ((float4*)outv)[(long)g * 16 + lane * 2 + 1] = make_float4(r[4], r[5], r[6], r[7]);
    }
}

// ---------------- fused MLP (half I/O): X = half(dinv ⊙ relu(X W1 + b1) W2) ----------------
// 64-row tile, 256 threads, 4 rows x 8 cols per thread. In-place (T==G) safe:
// block writes only its own rows after staging them.
__global__ __launch_bounds__(256) void k_mlp_h(const __half* __restrict__ G,   // [N,64]
                                               const float* __restrict__ W1,   // [64,128]
                                               const float* __restrict__ b1,   // [128]
                                               const float* __restrict__ W2,   // [128,64]
                                               const float* __restrict__ dscale,
                                               __half* __restrict__ T,         // [N,64]
                                               int M) {
    __shared__ float Ws[64 * 128];   // 32 KB: W1, then W2
    __shared__ float HA[64 * 132];   // 33 KB: A tile (stride 68), then H tile (stride 132)
    const int tid = threadIdx.x;
    const int row0 = blockIdx.x * 64;
    const int ty = tid >> 4;
    const int tx = tid & 15;

    // stage A tile: 64 rows x 64 halves = 512 x 16B units, 2/thread; convert to fp32
    #pragma unroll
    for (int l = 0; l < 2; ++l) {
        int idx = l * 256 + tid;
        int r = idx >> 3, seg = idx & 7;
        int gr = row0 + r;
        float4 raw = make_float4(0.f, 0.f, 0.f, 0.f);   // 0 bits == +0.0 halves
        if (gr < M) raw = ((const float4*)G)[(long)gr * 8 + seg];
        float f[8] = {};
        h8_add(raw, f);
        *(float4*)&HA[r * 68 + seg * 8]     = make_float4(f[0], f[1], f[2], f[3]);
        *(float4*)&HA[r * 68 + seg * 8 + 4] = make_float4(f[4], f[5], f[6], f[7]);
    }
    #pragma unroll
    for (int l = 0; l < 8; ++l) {
        int idx = (l * 256 + tid) * 4;
        *(float4*)&Ws[idx] = *(const float4*)&W1[idx];
    }
    __syncthreads();

    float4 accA[4], accB[4];
    #pragma unroll
    for (int i = 0; i < 4; ++i) {
        accA[i] = make_float4(0.f, 0.f, 0.f, 0.f);
        accB[i] = make_float4(0.f, 0.f, 0.f, 0.f);
    }
    for (int k4 = 0; k4 < 64; k4 += 4) {
        float4 a[4];
        #pragma unroll
        for (int i = 0; i < 4; ++i) a[i] = *(const float4*)&HA[(ty * 4 + i) * 68 + k4];
        #pragma unroll
        for (int kk = 0; kk < 4; ++kk) {
            const float* wr = &Ws[(k4 + kk) * 128 + tx * 8];
            float4 wA = *(const float4*)wr;
            float4 wB = *(const float4*)(wr + 4);
            #pragma unroll
            for (int i = 0; i < 4; ++i) {
                float ak = (&a[i].x)[kk];
                accA[i].x += ak * wA.x; accA[i].y += ak * wA.y;
                accA[i].z += ak * wA.z; accA[i].w += ak * wA.w;
                accB[i].x += ak * wB.x; accB[i].y += ak * wB.y;
                accB[i].z += ak * wB.z; accB[i].w += ak * wB.w;
            }
        }
    }
    __syncthreads();

    {
        float4 bA = *(const float4*)&b1[tx * 8];
        float4 bB = *(const float4*)&b1[tx * 8 + 4];
        #pragma unroll
        for (int i = 0; i < 4; ++i) {
            float4 hA = make_float4(fmaxf(accA[i].x + bA.x, 0.f), fmaxf(accA[i].y + bA.y, 0.f),
                                    fmaxf(accA[i].z + bA.z, 0.f), fmaxf(accA[i].w + bA.w, 0.f));
            float4 hB = make_float4(fmaxf(accB[i].x + bB.x, 0.f), fmaxf(accB[i].y + bB.y, 0.f),
                                    fmaxf(accB[i].z + bB.z, 0.f), fmaxf(accB[i].w + bB.w, 0.f));
            *(float4*)&HA[(ty * 4 + i) * 132 + tx * 8 + 0] = hA;
            *(float4*)&HA[(ty * 4 + i) * 132 + tx * 8 + 4] = hB;
        }
    }
    #pragma unroll
    for (int l = 0; l < 8; ++l) {
        int idx = (l * 256 + tid) * 4;
        *(float4*)&Ws[idx] = *(const float4*)&W2[idx];
    }
    __syncthreads();

    float4 o[4];
    #pragma unroll
    for (int i = 0; i < 4; ++i) o[i] = make_float4(0.f, 0.f, 0.f, 0.f);
    for (int k4 = 0; k4 < 128; k4 += 4) {
        float4 a[4];
        #pragma unroll
        for (int i = 0; i < 4; ++i) a[i] = *(const float4*)&HA[(ty * 4 + i) * 132 + k4];
        #pragma unroll
        for (int kk = 0; kk < 4; ++kk) {
            float4 w = *(const float4*)&Ws[(k4 + kk) * 64 + tx * 4];
            #pragma unroll
            for (int i = 0; i < 4; ++i) {
                float ak = (&a[i].x)[kk];
                o[i].x += ak * w.x; o[i].y += ak * w.y;
                o[i].z += ak * w.z; o[i].w += ak * w.w;
            }
        }
    }
    #pragma unroll
    for (int i = 0; i < 4; ++i) {
        int gr = row0 + ty * 4 + i;
        if (gr < M) {
            float sc = dscale[gr];
            __half2 p0 = __float22half2_rn(make_float2(o[i].x * sc, o[i].y * sc));
            __half2 p1 = __float22half2_rn(make_float2(o[i].z * sc, o[i].w * sc));
            float2 st;
            ((__half2*)&st)[0] = p0;
            ((__half2*)&st)[1] = p1;
            *(float2*)(T + (long)gr * 64 + tx * 4) = st;
        }
    }
}

// ---------------- fallback path (float, atomic scatter; only if ws too small) ----------------
__global__ __launch_bounds__(256) void k_init_deg(float* deg, int n) {
    int i = blockIdx.x * 256 + threadIdx.x;
    if (i < n) deg[i] = 1.0f;
}
__global__ __launch_bounds__(256) void k_count_deg(const int* __restrict__ ei, float* deg, int E) {
    int e = blockIdx.x * 256 + threadIdx.x;
    if (e < E) atomAddF(&deg[ei[E + e]], 1.0f);
}
__global__ __launch_bounds__(256) void k_rsqrt(float* deg, int n) {
    int i = blockIdx.x * 256 + threadIdx.x;
    if (i < n) deg[i] = rsqrtf(deg[i]);
}
template<bool BIAS>
__global__ __launch_bounds__(256) void k_self(const float* __restrict__ src,
                                              const float* __restrict__ dinv,
                                              const float* __restrict__ b,
                                              float* __restrict__ out, int n) {
    int g = blockIdx.x * 256 + threadIdx.x;
    int i = g >> 4, c = g & 15;
    if (i >= n) return;
    float di = dinv[i];
    float s = di * di;
    float4 v = *(const float4*)&src[(long)i * DIM + c * 4];
    float4 r = make_float4(v.x * s, v.y * s, v.z * s, v.w * s);
    if (BIAS) {
        float4 bv = *(const float4*)&b[c * 4];
        r.x += bv.x; r.y += bv.y; r.z += bv.z; r.w += bv.w;
    }
    *(float4*)&out[(long)i * DIM + c * 4] = r;
}
__global__ __launch_bounds__(256) void k_edge_agg(const int* __restrict__ ei,
                                                  const float* __restrict__ dinv,
                                                  const float* __restrict__ h,
                                                  float* __restrict__ out, int E) {
    int t = threadIdx.x;
    int e = blockIdx.x * 16 + (t >> 4);
    if (e >= E) return;
    int lane = t & 15;
    int s = ei[e];
    int d = ei[E + e];
    float norm = dinv[s] * dinv[d];
    float4 hv = *(const float4*)&h[(long)s * DIM + lane * 4];
    float* o = &out[(long)d * DIM + lane * 4];
    atomAddF(o + 0, hv.x * norm);
    atomAddF(o + 1, hv.y * norm);
    atomAddF(o + 2, hv.z * norm);
    atomAddF(o + 3, hv.w * norm);
}
// float-I/O MLP for the fallback path
__global__ __launch_bounds__(256) void k_mlp_f(const float* __restrict__ G,
                                               const float* __restrict__ W1,
                                               const float* __restrict__ b1,
                                               const float* __restrict__ W2,
                                               float* __restrict__ T, int M) {
    __shared__ float Ws[64 * 128];
    __shared__ float HA[64 * 132];
    const int tid = threadIdx.x;
    const int row0 = blockIdx.x * 64;
    const int ty = tid >> 4;
    const int tx = tid & 15;
    #pragma unroll
    for (int l = 0; l < 4; ++l) {
        int idx = l * 256 + tid;
        int r = idx >> 4, cv = idx & 15;
        int gr = row0 + r;
        float4 v = make_float4(0.f, 0.f, 0.f, 0.f);
        if (gr < M) v = *(const float4*)&G[(long)gr * DIM + cv * 4];
        *(float4*)&HA[r * 68 + cv * 4] = v;
    }
    #pragma unroll
    for (int l = 0; l < 8; ++l) {
        int idx = (l * 256 + tid) * 4;
        *(float4*)&Ws[idx] = *(const float4*)&W1[idx];
    }
    __syncthreads();
    float4 accA[4], accB[4];
    #pragma unroll
    for (int i = 0; i < 4; ++i) {
        accA[i] = make_float4(0.f, 0.f, 0.f, 0.f);
        accB[i] = make_float4(0.f, 0.f, 0.f, 0.f);
    }
    for (int k4 = 0; k4 < 64; k4 += 4) {
        float4 a[4];
        #pragma unroll
        for (int i = 0; i < 4; ++i) a[i] = *(const float4*)&HA[(ty * 4 + i) * 68 + k4];
        #pragma unroll
        for (int kk = 0; kk < 4; ++kk) {
            const float* wr = &Ws[(k4 + kk) * 128 + tx * 8];
            float4 wA = *(const float4*)wr;
            float4 wB = *(const float4*)(wr + 4);
            #pragma unroll
            for (int i = 0; i < 4; ++i) {
                float ak = (&a[i].x)[kk];
                accA[i].x += ak * wA.x; accA[i].y += ak * wA.y;
                accA[i].z += ak * wA.z; accA[i].w += ak * wA.w;
                accB[i].x += ak * wB.x; accB[i].y += ak * wB.y;
                accB[i].z += ak * wB.z; accB[i].w += ak * wB.w;
            }
        }
    }
    __syncthreads();
    {
        float4 bA = *(const float4*)&b1[tx * 8];
        float4 bB = *(const float4*)&b1[tx * 8 + 4];
        #pragma unroll
        for (int i = 0; i < 4; ++i) {
            float4 hA = make_float4(fmaxf(accA[i].x + bA.x, 0.f), fmaxf(accA[i].y + bA.y, 0.f),
                                    fmaxf(accA[i].z + bA.z, 0.f), fmaxf(accA[i].w + bA.w, 0.f));
            float4 hB = make_float4(fmaxf(accB[i].x + bB.x, 0.f), fmaxf(accB[i].y + bB.y, 0.f),
                                    fmaxf(accB[i].z + bB.z, 0.f), fmaxf(accB[i].w + bB.w, 0.f));
            *(float4*)&HA[(ty * 4 + i) * 132 + tx * 8 + 0] = hA;
            *(float4*)&HA[(ty * 4 + i) * 132 + tx * 8 + 4] = hB;
        }
    }
    #pragma unroll
    for (int l = 0; l < 8; ++l) {
        int idx = (l * 256 + tid) * 4;
        *(float4*)&Ws[idx] = *(const float4*)&W2[idx];
    }
    __syncthreads();
    float4 o[4];
    #pragma unroll
    for (int i = 0; i < 4; ++i) o[i] = make_float4(0.f, 0.f, 0.f, 0.f);
    for (int k4 = 0; k4 < 128; k4 += 4) {
        float4 a[4];
        #pragma unroll
        for (int i = 0; i < 4; ++i) a[i] = *(const float4*)&HA[(ty * 4 + i) * 132 + k4];
        #pragma unroll
        for (int kk = 0; kk < 4; ++kk) {
            float4 w = *(const float4*)&Ws[(k4 + kk) * 64 + tx * 4];
            #pragma unroll
            for (int i = 0; i < 4; ++i) {
                float ak = (&a[i].x)[kk];
                o[i].x += ak * w.x; o[i].y += ak * w.y;
                o[i].z += ak * w.z; o[i].w += ak * w.w;
            }
        }
    }
    #pragma unroll
    for (int i = 0; i < 4; ++i) {
        int gr = row0 + ty * 4 + i;
        if (gr < M) *(float4*)&T[(long)gr * DIM + tx * 4] = o[i];
    }
}

extern "C" void kernel_launch(void* const* d_in, const int* in_sizes, int n_in,
                              void* d_out, int out_size, void* d_ws, size_t ws_size,
                              hipStream_t stream) {
    const float* x  = (const float*)d_in[0];
    const int*   ei = (const int*)d_in[1];   // [2,E] int32
    const float* W1 = (const float*)d_in[2];
    const float* b1 = (const float*)d_in[3];
    const float* W2 = (const float*)d_in[4];
    const float* b2 = (const float*)d_in[5];
    float* out = (float*)d_out;

    const int N = in_sizes[0] / DIM;   // 100000
    const int E = in_sizes[1] / 2;     // 1600000

    const int gn   = (N + 255) / 256;
    const int ge   = (E + 255) / 256;
    const int gagg = (N + 31) / 32;
    const int gmlp = (N + 63) / 64;
    const int grow8 = ((long)N * 8 + 255) / 256;   // 8 lanes/row prescale
    const int gbk  = (E + BK_TILE - 1) / BK_TILE;

    // ws layout (256B-aligned bump). pairs alias Y (pairs dead before prescale).
    size_t off = 0;
    auto bump = [&](size_t bytes) { size_t o = off; off = (off + bytes + 255) & ~(size_t)255; return o; };
    size_t o_dinv   = bump((size_t)N * 4);
    size_t o_rowptr = bump((size_t)(N + 1) * 4);
    size_t o_bcnt   = bump(NB * 4);
    size_t o_bbase  = bump((NB + 1) * 4);
    size_t o_gcur   = bump(NB * 4);
    size_t o_col    = bump((size_t)E * 4);
    size_t o_X      = bump((size_t)N * DIM * 2);   // half agg1-out / MLP in+out
    size_t o_Y      = bump((size_t)N * DIM * 2);   // half prescaled x; >= E*4 (12.8MB >= 6.4MB)
    size_t need_csr = off;                         // ~32.9 MB (proven budget)

    char* ws = (char*)d_ws;

    if (ws_size >= need_csr) {
        float*    dinv   = (float*)(ws + o_dinv);
        int*      rowptr = (int*)(ws + o_rowptr);
        int*      bcnt   = (int*)(ws + o_bcnt);
        int*      bbase  = (int*)(ws + o_bbase);
        int*      gcur   = (int*)(ws + o_gcur);
        int*      col    = (int*)(ws + o_col);
        __half*   X      = (__half*)(ws + o_X);
        __half*   Y      = (__half*)(ws + o_Y);
        unsigned* pairs  = (unsigned*)(ws + o_Y);  // alias (dead after k_finish)

        k_zero256<<<1, 256, 0, stream>>>(bcnt);
        k_hist256<<<gbk, 256, 0, stream>>>(ei, bcnt, E);
        k_scan_b<<<1, 256, 0, stream>>>(bcnt, bbase, gcur);
        k_bucket<<<gbk, 256, 0, stream>>>(ei, gcur, pairs, E);
        k_finish<<<NB, 256, 0, stream>>>(pairs, bbase, rowptr, dinv, col, N);

        // Y = half(dinv ⊙ x)
        k_prescale_h<<<grow8, 256, 0, stream>>>(x, dinv, Y, N);
        // X = half( dinv[d]*(Y[d] + sum Y[s]) )   == half(Ahat x)
        k_agg_h<false, true><<<gagg, 256, 0, stream>>>(rowptr, col, dinv, Y, nullptr, X, N);
        // X = half( dinv ⊙ relu(X W1 + b1) W2 )   (in-place, tile-local)
        k_mlp_h<<<gmlp, 256, 0, stream>>>(X, W1, b1, W2, dinv, X, N);
        // out = dinv[d]*(X[d] + sum X[s]) + b2
        k_agg_h<true, false><<<gagg, 256, 0, stream>>>(rowptr, col, dinv, X, b2, out, N);
    } else {
        // -------- fallback (float atomic scatter) --------
        float* dinv = (float*)ws;
        float* buf  = (float*)(ws + 512 * 1024);
        int grow16 = ((long)N * 16 + 255) / 256;
        int gedge = (E + 15) / 16;

        k_init_deg<<<gn, 256, 0, stream>>>(dinv, N);
        k_count_deg<<<ge, 256, 0, stream>>>(ei, dinv, E);
        k_rsqrt<<<gn, 256, 0, stream>>>(dinv, N);

        k_self<false><<<grow16, 256, 0, stream>>>(x, dinv, nullptr, buf, N);
        k_edge_agg<<<gedge, 256, 0, stream>>>(ei, dinv, x, buf, E);
        k_mlp_f<<<gmlp, 256, 0, stream>>>(buf, W1, b1, W2, buf, N);
        k_self<true><<<grow16, 256, 0, stream>>>(buf, dinv, b2, out, N);
        k_edge_agg<<<gedge, 256, 0, stream>>>(ei, dinv, buf, out, E);
    }
}